// Round 12
// baseline (123.779 us; speedup 1.0000x reference)
//
#include <hip/hip_runtime.h>

#define THREADS 512
#define HW 16384        // H*W per (b,c) row
#define K_SEL 8192u     // k = 0.5 * H * W
#define NB1 2048        // pass-1: abs bits [30:20]
#define NB2 128         // pass-2: bits [19:13]
#define NB3 128         // pass-3: bits [12:6]
#define NB4 64          // pass-4: bits [5:0]
#define VPT 8           // uint4 per thread (32 floats); THREADS*VPT*4 == HW
#define CAP 1024        // candidate-list capacity (exact fallback if exceeded)

static_assert(THREADS * VPT * 4 == HW, "row tiling");

typedef unsigned uint32x4 __attribute__((ext_vector_type(4)));  // NT-store-compatible

// Two-stage parallel bin search, executed by wave 0 only; result broadcast
// via LDS. Bins ascend in value; finds the bin holding the kRem-th LARGEST
// element and the residual rank within it. ALL cross-lane ops are convergent;
// only the final LDS write is guarded. Handles bpl==1 (NBINS==64) correctly.
template <int NBINS>
__device__ __forceinline__ void find_bin_wave0(const unsigned* __restrict__ hist,
                                               unsigned kRem, unsigned* __restrict__ bc) {
  constexpr int bpl = NBINS >> 6;             // bins per lane (>=1)
  const int lane = (int)(threadIdx.x & 63);
  const int base = lane * bpl;
  unsigned s = 0;
#pragma unroll
  for (int j = 0; j < bpl; ++j) s += hist[base + ((j + lane) & (bpl - 1))];
  unsigned suf = s;                            // inclusive suffix sum over lanes
#pragma unroll
  for (int off = 1; off < 64; off <<= 1) {
    unsigned w = __shfl_down(suf, off);
    if (lane + off < 64) suf += w;
  }
  const unsigned cumAbove = suf - s;
  const bool hit = (cumAbove < kRem) && (kRem <= suf);
  const unsigned long long m = __ballot(hit);
  const int tl = (int)__builtin_ctzll(m);      // unique target chunk
  const unsigned cumTl = __shfl(cumAbove, tl);
  const int j = (bpl > 1) ? (lane & (bpl - 1)) : 0;
  const unsigned h = hist[tl * bpl + j];
  unsigned sufc = h;
#pragma unroll
  for (int off = 1; off < 32; off <<= 1) {
    if (off < bpl) {
      unsigned w = __shfl_down(sufc, off);
      if (j + off < bpl) sufc += w;
    }
  }
  const unsigned cumW = sufc - h;
  const bool hit2 = ((cumTl + cumW) < kRem) && (kRem <= cumTl + cumW + h);
  const unsigned long long m2 = __ballot(hit2);
  const int jl = (bpl > 1) ? ((int)__builtin_ctzll(m2) & (bpl - 1)) : 0;
  const unsigned kw = __shfl(cumW, jl);        // convergent
  if (lane == 0) {
    bc[0] = (unsigned)(tl * bpl + jl);
    bc[1] = kRem - cumTl - kw;
  }
}

extern "C" __global__ __launch_bounds__(THREADS, 4)
void sparsify_topk_kernel(const float* __restrict__ x, float* __restrict__ out) {
  __shared__ __align__(16) unsigned data[HW];   // staged row (|raw bits|)
  __shared__ unsigned h1[NB1];
  __shared__ unsigned h2[NB2];
  __shared__ unsigned h3[NB3];
  __shared__ unsigned h4[NB4];
  __shared__ unsigned list[CAP];                // candidates: (a>>20)==T1
  __shared__ unsigned bc[2];
  __shared__ unsigned cnt;

  uint4* data4 = (uint4*)data;
  const int t = (int)threadIdx.x;
  const size_t rowOff = (size_t)blockIdx.x * (HW / 4);
  const uint4*    src = (const uint4*)x + rowOff;
  uint32x4*       dst = (uint32x4*)out + rowOff;

  // Zero hists + counter.
#pragma unroll
  for (int i = 0; i < NB1 / THREADS; ++i) h1[t + i * THREADS] = 0;
  if (t < NB2) h2[t] = 0;
  if (t < NB3) h3[t] = 0;
  if (t < NB4) h4[t] = 0;
  if (t == 0) cnt = 0;
  __syncthreads();

  // Stage: single global read -> LDS, h1 built from the load registers.
#pragma unroll
  for (int i = 0; i < VPT; ++i) {
    const uint4 u = src[i * THREADS + t];
    data4[i * THREADS + t] = u;
    atomicAdd(&h1[(u.x & 0x7fffffffu) >> 20], 1u);
    atomicAdd(&h1[(u.y & 0x7fffffffu) >> 20], 1u);
    atomicAdd(&h1[(u.z & 0x7fffffffu) >> 20], 1u);
    atomicAdd(&h1[(u.w & 0x7fffffffu) >> 20], 1u);
  }
  __syncthreads();
  if (t < 64) find_bin_wave0<NB1>(h1, K_SEL, bc);
  __syncthreads();
  const unsigned T1 = bc[0];
  unsigned kRem = bc[1];

  // P2 scan (LDS): matching elements -> candidate list + h2 (bits [19:13]).
  // h2 is ALWAYS complete (unguarded), so find2 is exact even on overflow.
#pragma unroll
  for (int i = 0; i < HW / 4 / THREADS; ++i) {
    const uint4 u = data4[i * THREADS + t];
    unsigned a;
#define P2_ONE(comp)                                                    \
    a = u.comp & 0x7fffffffu;                                           \
    if ((a >> 20) == T1) {                                              \
      atomicAdd(&h2[(a >> 13) & (NB2 - 1)], 1u);                        \
      const unsigned idx = atomicAdd(&cnt, 1u);                         \
      if (idx < CAP) list[idx] = a;                                     \
    }
    P2_ONE(x) P2_ONE(y) P2_ONE(z) P2_ONE(w)
#undef P2_ONE
  }
  __syncthreads();
  if (t < 64) find_bin_wave0<NB2>(h2, kRem, bc);
  __syncthreads();
  const unsigned pref2 = (T1 << 7) | bc[0];     // == a>>13 of threshold
  kRem = bc[1];
  const unsigned nC = cnt;                      // block-uniform after barrier
  const bool fallback = (nC > CAP);

  // P3: bits [12:6] of (a>>13)==pref2 -> h3. List path or exact fallback.
  if (!fallback) {
    for (unsigned i = t; i < nC; i += THREADS) {
      const unsigned a = list[i];
      if ((a >> 13) == pref2) atomicAdd(&h3[(a >> 6) & (NB3 - 1)], 1u);
    }
  } else {
#pragma unroll
    for (int i = 0; i < HW / 4 / THREADS; ++i) {
      const uint4 u = data4[i * THREADS + t];
      unsigned a;
      a = u.x & 0x7fffffffu; if ((a >> 13) == pref2) atomicAdd(&h3[(a >> 6) & (NB3 - 1)], 1u);
      a = u.y & 0x7fffffffu; if ((a >> 13) == pref2) atomicAdd(&h3[(a >> 6) & (NB3 - 1)], 1u);
      a = u.z & 0x7fffffffu; if ((a >> 13) == pref2) atomicAdd(&h3[(a >> 6) & (NB3 - 1)], 1u);
      a = u.w & 0x7fffffffu; if ((a >> 13) == pref2) atomicAdd(&h3[(a >> 6) & (NB3 - 1)], 1u);
    }
  }
  __syncthreads();
  if (t < 64) find_bin_wave0<NB3>(h3, kRem, bc);
  __syncthreads();
  const unsigned pref3 = (pref2 << 7) | bc[0];  // == a>>6 of threshold
  kRem = bc[1];

  // P4: bits [5:0] of (a>>6)==pref3 -> h4.
  if (!fallback) {
    for (unsigned i = t; i < nC; i += THREADS) {
      const unsigned a = list[i];
      if ((a >> 6) == pref3) atomicAdd(&h4[a & (NB4 - 1)], 1u);
    }
  } else {
#pragma unroll
    for (int i = 0; i < HW / 4 / THREADS; ++i) {
      const uint4 u = data4[i * THREADS + t];
      unsigned a;
      a = u.x & 0x7fffffffu; if ((a >> 6) == pref3) atomicAdd(&h4[a & (NB4 - 1)], 1u);
      a = u.y & 0x7fffffffu; if ((a >> 6) == pref3) atomicAdd(&h4[a & (NB4 - 1)], 1u);
      a = u.z & 0x7fffffffu; if ((a >> 6) == pref3) atomicAdd(&h4[a & (NB4 - 1)], 1u);
      a = u.w & 0x7fffffffu; if ((a >> 6) == pref3) atomicAdd(&h4[a & (NB4 - 1)], 1u);
    }
  }
  __syncthreads();
  if (t < 64) find_bin_wave0<NB4>(h4, kRem, bc);
  __syncthreads();
  const unsigned thr = (pref3 << 6) | bc[0];    // exact k-th largest |x| bits

  // Mask pass from LDS; NON-TEMPORAL store (>= keeps ties, as reference).
#pragma unroll
  for (int i = 0; i < VPT; ++i) {
    const uint4 u = data4[i * THREADS + t];
    uint32x4 w;
    w.x = ((u.x & 0x7fffffffu) >= thr) ? u.x : 0u;
    w.y = ((u.y & 0x7fffffffu) >= thr) ? u.y : 0u;
    w.z = ((u.z & 0x7fffffffu) >= thr) ? u.z : 0u;
    w.w = ((u.w & 0x7fffffffu) >= thr) ? u.w : 0u;
    __builtin_nontemporal_store(w, &dst[i * THREADS + t]);
  }
}

extern "C" void kernel_launch(void* const* d_in, const int* in_sizes, int n_in,
                              void* d_out, int out_size, void* d_ws, size_t ws_size,
                              hipStream_t stream) {
  (void)n_in; (void)d_ws; (void)ws_size; (void)out_size;
  const float* x = (const float*)d_in[0];
  float* out = (float*)d_out;
  const int rows = in_sizes[0] / HW;   // 4096
  sparsify_topk_kernel<<<dim3(rows), dim3(THREADS), 0, stream>>>(x, out);
}